// Round 2
// baseline (678.470 us; speedup 1.0000x reference)
//
#include <hip/hip_runtime.h>

// Attention_41601053229865 — fused 3D channel attention.
// B=2 (processed sequentially to halve workspace), C=192 (4 heads x 48),
// spatial 32^3 = 32768. fp32 compute; intermediate storage fp32 or bf16
// depending on ws_size.

typedef unsigned short bfr;   // raw bf16 storage

constexpr int C = 192, C3 = 576, S = 32, HEADS = 4, CH = 48;
constexpr long N = 32768;            // 32^3
constexpr long CHN = (long)C3 * N;   // per-batch big buffer elems (18,874,368)
#define EPSN 1e-12f

__device__ __forceinline__ float bf2f(bfr h) { return __uint_as_float(((unsigned)h) << 16); }
__device__ __forceinline__ bfr f2bf(float f) {
    unsigned u = __float_as_uint(f);
    return (bfr)((u + 0x7fffu + ((u >> 16) & 1u)) >> 16);
}
__device__ __forceinline__ float ld1(const float* p) { return *p; }
__device__ __forceinline__ float ld1(const bfr* p) { return bf2f(*p); }
__device__ __forceinline__ void st1(float* p, float v) { *p = v; }
__device__ __forceinline__ void st1(bfr* p, float v) { *p = f2bf(v); }
__device__ __forceinline__ float4 ld4(const float* p) { return *reinterpret_cast<const float4*>(p); }
__device__ __forceinline__ float4 ld4(const bfr* p) {
    ushort4 u = *reinterpret_cast<const ushort4*>(p);
    float4 r; r.x = bf2f(u.x); r.y = bf2f(u.y); r.z = bf2f(u.z); r.w = bf2f(u.w); return r;
}
__device__ __forceinline__ void st4(float* p, float4 v) { *reinterpret_cast<float4*>(p) = v; }
__device__ __forceinline__ void st4(bfr* p, float4 v) {
    ushort4 u; u.x = f2bf(v.x); u.y = f2bf(v.y); u.z = f2bf(v.z); u.w = f2bf(v.w);
    *reinterpret_cast<ushort4*>(p) = u;
}

// ---------------------------------------------------------------------------
// GEMM: Y[o][n] = bias[o] + sum_k A[o][k] * X[k][n]   (single batch)
// 64x64 tile, K-chunks of 16, 256 threads, 4x4 per thread.
template <typename TX, typename TY>
__global__ __launch_bounds__(256) void gemm_cn(
    const float* __restrict__ A, const float* __restrict__ bias,
    const TX* __restrict__ X, TY* __restrict__ Y, int K)
{
    __shared__ float sW[16][64];   // [k][o]
    __shared__ float sX[16][64];   // [k][n]
    const int o0 = blockIdx.y * 64;
    const long n0 = (long)blockIdx.x * 64;
    const int tid = threadIdx.x;
    const int tx = tid & 15, ty = tid >> 4;

    float acc[4][4] = {};
    for (int kc = 0; kc < K; kc += 16) {
        {   // stage W tile transposed to [k][o]
            const int o = tid >> 2, k4 = (tid & 3) * 4;
            const float4 w4 = ld4(A + (long)(o0 + o) * K + kc + k4);
            sW[k4 + 0][o] = w4.x; sW[k4 + 1][o] = w4.y;
            sW[k4 + 2][o] = w4.z; sW[k4 + 3][o] = w4.w;
        }
        {   // stage X tile
            const int k = tid >> 4, nn = (tid & 15) * 4;
            st4(&sX[k][nn], ld4(X + (kc + k) * N + n0 + nn));
        }
        __syncthreads();
#pragma unroll
        for (int kk = 0; kk < 16; ++kk) {
            const float4 a  = *reinterpret_cast<const float4*>(&sW[kk][ty * 4]);
            const float4 xv = *reinterpret_cast<const float4*>(&sX[kk][tx * 4]);
            acc[0][0] += a.x * xv.x; acc[0][1] += a.x * xv.y; acc[0][2] += a.x * xv.z; acc[0][3] += a.x * xv.w;
            acc[1][0] += a.y * xv.x; acc[1][1] += a.y * xv.y; acc[1][2] += a.y * xv.z; acc[1][3] += a.y * xv.w;
            acc[2][0] += a.z * xv.x; acc[2][1] += a.z * xv.y; acc[2][2] += a.z * xv.z; acc[2][3] += a.z * xv.w;
            acc[3][0] += a.w * xv.x; acc[3][1] += a.w * xv.y; acc[3][2] += a.w * xv.z; acc[3][3] += a.w * xv.w;
        }
        __syncthreads();
    }
#pragma unroll
    for (int i = 0; i < 4; ++i) {
        const float bo = bias[o0 + ty * 4 + i];
        float4 r;
        r.x = acc[i][0] + bo; r.y = acc[i][1] + bo;
        r.z = acc[i][2] + bo; r.w = acc[i][3] + bo;
        st4(Y + (long)(o0 + ty * 4 + i) * N + n0 + tx * 4, r);
    }
}

// ---------------------------------------------------------------------------
// Depthwise 3x3x3 conv (cross-correlation, pad 1) + bias; fused q/k sumsq.
// One block per (ch, h-plane); 256 threads cover the 32x32 (w,d) plane x4.
template <typename T>
__global__ __launch_bounds__(256) void dwconv3(
    const T* __restrict__ in,       // [576][32][32][32]
    const float* __restrict__ w,    // [576][27]
    const float* __restrict__ bias, // [576]
    T* __restrict__ out,            // [576][32][32][32]
    float* __restrict__ sq)         // [384]
{
    __shared__ float sp[3][34][34];
    const int blk = blockIdx.x;
    const int h  = blk & 31;
    const int ch = blk >> 5;
    const T* base = in + (long)ch * N;
    const int tid = threadIdx.x;
    for (int i = tid; i < 34 * 34; i += 256) {
        const int pw = i / 34 - 1, pd = i % 34 - 1;
        const bool inwd = (pw >= 0) && (pw < 32) && (pd >= 0) && (pd < 32);
#pragma unroll
        for (int hp = 0; hp < 3; ++hp) {
            const int hh = h + hp - 1;
            float v = 0.f;
            if (inwd && hh >= 0 && hh < 32) v = ld1(base + hh * 1024 + pw * 32 + pd);
            sp[hp][i / 34][i % 34] = v;
        }
    }
    float wr[27];
#pragma unroll
    for (int j = 0; j < 27; ++j) wr[j] = w[ch * 27 + j];
    const float bs = bias[ch];
    __syncthreads();
    float ssq = 0.f;
    T* outp = out + ((long)ch * 32 + h) * 1024;
    for (int r = 0; r < 4; ++r) {
        const int j = tid + r * 256;
        const int ww = j >> 5, dd = j & 31;
        float acc2 = bs;
#pragma unroll
        for (int dh = 0; dh < 3; ++dh)
#pragma unroll
            for (int dw2 = 0; dw2 < 3; ++dw2)
#pragma unroll
                for (int dd2 = 0; dd2 < 3; ++dd2)
                    acc2 += wr[(dh * 3 + dw2) * 3 + dd2] * sp[dh][ww + dw2][dd + dd2];
        st1(outp + j, acc2);
        ssq += acc2 * acc2;
    }
    if (ch < 2 * C) {   // q or k channel
#pragma unroll
        for (int off = 32; off > 0; off >>= 1) ssq += __shfl_down(ssq, off, 64);
        __shared__ float wsum[4];
        if ((tid & 63) == 0) wsum[tid >> 6] = ssq;
        __syncthreads();
        if (tid == 0) atomicAdd(&sq[ch], wsum[0] + wsum[1] + wsum[2] + wsum[3]);
    }
}

// ---------------------------------------------------------------------------
// Raw gram partials: attn_raw[h,c,e] += sum_n q[c,n]*k[e,n]
// Grid: (h, 64 chunks of 512 n). 256 threads; 3x3 outputs each.
template <typename T>
__global__ __launch_bounds__(256) void attn_partial(
    const T* __restrict__ dwout, float* __restrict__ attn_raw)
{
    __shared__ float sq[48][68];
    __shared__ float sk[48][68];
    const int blk = blockIdx.x;
    const int chunk = blk & 63;
    const int h = blk >> 6;
    const T* qb = dwout + (long)(h * CH) * N + chunk * 512;
    const T* kb = qb + (long)C * N;
    const int tid = threadIdx.x;
    const int tx = tid & 15, ty = tid >> 4;
    float acc[3][3] = {};
    for (int n0 = 0; n0 < 512; n0 += 64) {
        for (int i = tid; i < 768; i += 256) {
            const int row = i >> 4, c4 = (i & 15) * 4;
            st4(&sq[row][c4], ld4(qb + (long)row * N + n0 + c4));
            st4(&sk[row][c4], ld4(kb + (long)row * N + n0 + c4));
        }
        __syncthreads();
#pragma unroll 16
        for (int kk = 0; kk < 64; ++kk) {
            float qv[3], kv[3];
#pragma unroll
            for (int i = 0; i < 3; ++i) qv[i] = sq[ty * 3 + i][kk];
#pragma unroll
            for (int j = 0; j < 3; ++j) kv[j] = sk[tx * 3 + j][kk];
#pragma unroll
            for (int i = 0; i < 3; ++i)
#pragma unroll
                for (int j = 0; j < 3; ++j) acc[i][j] += qv[i] * kv[j];
        }
        __syncthreads();
    }
    float* dst = attn_raw + (long)h * CH * CH;
#pragma unroll
    for (int i = 0; i < 3; ++i)
#pragma unroll
        for (int j = 0; j < 3; ++j)
            atomicAdd(&dst[(ty * 3 + i) * CH + tx * 3 + j], acc[i][j]);
}

// ---------------------------------------------------------------------------
// Scale by 1/(||q|| ||k||) * temperature, softmax over e. One row per thread.
__global__ __launch_bounds__(64) void softmax_scale(
    float* __restrict__ attn, const float* __restrict__ sq,
    const float* __restrict__ temp)
{
    const int h = blockIdx.x;
    const int c = threadIdx.x;
    if (c >= CH) return;
    const float invq = 1.0f / fmaxf(sqrtf(sq[h * CH + c]), EPSN);
    const float t = temp[h];
    float* row = attn + ((long)h * CH + c) * CH;
    float vals[CH];
    float mx = -3.4e38f;
#pragma unroll
    for (int e = 0; e < CH; ++e) {
        const float invk = 1.0f / fmaxf(sqrtf(sq[C + h * CH + e]), EPSN);
        const float v = row[e] * invq * invk * t;
        vals[e] = v;
        mx = fmaxf(mx, v);
    }
    float sum = 0.f;
#pragma unroll
    for (int e = 0; e < CH; ++e) { vals[e] = expf(vals[e] - mx); sum += vals[e]; }
    const float inv = 1.0f / sum;
#pragma unroll
    for (int e = 0; e < CH; ++e) row[e] = vals[e] * inv;
}

// ---------------------------------------------------------------------------
// M[o][h*48+e] = sum_c P[o][h*48+c] * attn[h][c][e]
__global__ __launch_bounds__(192) void build_m(
    const float* __restrict__ P, const float* __restrict__ attn,
    float* __restrict__ M)
{
    const int o = blockIdx.x;
    const int he = threadIdx.x;
    const int h = he / CH, e = he % CH;
    float s = 0.f;
#pragma unroll
    for (int cc = 0; cc < CH; ++cc)
        s += P[o * C + h * CH + cc] * attn[((long)h * CH + cc) * CH + e];
    M[(long)o * C + he] = s;
}

// ---------------------------------------------------------------------------
template <typename T>
static void run_batch(const float* x_b, const float* qkv_w, const float* qkv_b,
                      const float* dw_w, const float* dw_b,
                      const float* proj_w, const float* proj_b, const float* temp,
                      T* qkv, T* dwout, float* sq, float* attn, float* M,
                      float* out_b, hipStream_t stream)
{
    // 1) qkv = conv1x1(x)
    gemm_cn<float, T><<<dim3((unsigned)(N / 64), C3 / 64), 256, 0, stream>>>(
        qkv_w, qkv_b, x_b, qkv, C);
    // 2) depthwise 3x3x3 + bias, fused q/k sumsq
    dwconv3<T><<<C3 * S, 256, 0, stream>>>(qkv, dw_w, dw_b, dwout, sq);
    // 3) raw gram q.k^T partials
    attn_partial<T><<<HEADS * 64, 256, 0, stream>>>(dwout, attn);
    // 4) normalize + temperature + softmax
    softmax_scale<<<HEADS, 64, 0, stream>>>(attn, sq, temp);
    // 5) M = P_head @ attn  (fold proj into attention)
    build_m<<<C, 192, 0, stream>>>(proj_w, attn, M);
    // 6) out = M @ v + proj_b
    gemm_cn<T, float><<<dim3((unsigned)(N / 64), C / 64), 256, 0, stream>>>(
        M, proj_b, dwout + 2L * C * N, out_b, C);
}

extern "C" void kernel_launch(void* const* d_in, const int* in_sizes, int n_in,
                              void* d_out, int out_size, void* d_ws, size_t ws_size,
                              hipStream_t stream)
{
    const float* x      = (const float*)d_in[0];
    const float* qkv_w  = (const float*)d_in[1];
    const float* qkv_b  = (const float*)d_in[2];
    const float* dw_w   = (const float*)d_in[3];
    const float* dw_b   = (const float*)d_in[4];
    const float* proj_w = (const float*)d_in[5];
    const float* proj_b = (const float*)d_in[6];
    const float* temp   = (const float*)d_in[7];
    float* out = (float*)d_out;

    // small buffers first (shared by both paths)
    float* sq   = (float*)d_ws;            // [2][384]
    float* attn = sq + 2 * 384;            // [2][4][48][48]
    float* M    = attn + 2 * HEADS * CH * CH; // [2][192][192]
    char*  big  = (char*)(M + 2 * C * C);
    const size_t small_bytes = (size_t)((char*)big - (char*)d_ws);

    // zero the atomic accumulators (sq + attn)
    hipMemsetAsync(d_ws, 0, (2 * 384 + 2 * HEADS * CH * CH) * sizeof(float), stream);

    const size_t need_f32 = small_bytes + 2 * (size_t)CHN * sizeof(float);
    const bool fp32_path = ws_size >= need_f32;

    for (int b = 0; b < 2; ++b) {
        const float* x_b   = x + (long)b * C * N;
        float*       out_b = out + (long)b * C * N;
        float* sq_b   = sq + b * 384;
        float* attn_b = attn + b * HEADS * CH * CH;
        float* M_b    = M + b * C * C;
        if (fp32_path) {
            float* qkv   = (float*)big;
            float* dwout = qkv + CHN;
            run_batch<float>(x_b, qkv_w, qkv_b, dw_w, dw_b, proj_w, proj_b, temp,
                             qkv, dwout, sq_b, attn_b, M_b, out_b, stream);
        } else {
            bfr* qkv   = (bfr*)big;
            bfr* dwout = qkv + CHN;
            run_batch<bfr>(x_b, qkv_w, qkv_b, dw_w, dw_b, proj_w, proj_b, temp,
                           qkv, dwout, sq_b, attn_b, M_b, out_b, stream);
        }
    }
}

// Round 3
// 459.610 us; speedup vs baseline: 1.4762x; 1.4762x over previous
//
#include <hip/hip_runtime.h>

// Attention_41601053229865 — fused 3D channel attention, bf16-MFMA version.
// B=2 (sequential), C=192 (4 heads x 48), spatial 32^3 = 32768.

typedef unsigned short bfr;   // raw bf16 storage

constexpr int C = 192, C3 = 576, S = 32, HEADS = 4, CH = 48;
constexpr long N = 32768;            // 32^3
#define EPSN 1e-12f

using short8 = __attribute__((ext_vector_type(8))) short;
using f32x4  = __attribute__((ext_vector_type(4))) float;

__device__ __forceinline__ float bf2f(bfr h) { return __uint_as_float(((unsigned)h) << 16); }
__device__ __forceinline__ bfr f2bf(float f) {
    unsigned u = __float_as_uint(f);
    return (bfr)((u + 0x7fffu + ((u >> 16) & 1u)) >> 16);
}
__device__ __forceinline__ float ld1(const float* p) { return *p; }
__device__ __forceinline__ float ld1(const bfr* p) { return bf2f(*p); }
__device__ __forceinline__ void st1(float* p, float v) { *p = v; }
__device__ __forceinline__ void st1(bfr* p, float v) { *p = f2bf(v); }
__device__ __forceinline__ float4 ld4(const float* p) { return *reinterpret_cast<const float4*>(p); }
__device__ __forceinline__ float4 ld4(const bfr* p) {
    ushort4 u = *reinterpret_cast<const ushort4*>(p);
    float4 r; r.x = bf2f(u.x); r.y = bf2f(u.y); r.z = bf2f(u.z); r.w = bf2f(u.w); return r;
}

__device__ __forceinline__ f32x4 mfma16(short8 a, short8 b, f32x4 c) {
    return __builtin_amdgcn_mfma_f32_16x16x32_bf16(a, b, c, 0, 0, 0);
}

// ---------------------------------------------------------------------------
// Flat fp32 -> bf16 convert (for weights / M). n4 = count/4.
__global__ __launch_bounds__(256) void convert_bf(
    const float* __restrict__ in, bfr* __restrict__ out, int n4)
{
    const int i = blockIdx.x * 256 + threadIdx.x;
    if (i < n4) {
        const float4 v = *reinterpret_cast<const float4*>(in + (long)i * 4);
        ushort4 u;
        u.x = f2bf(v.x); u.y = f2bf(v.y); u.z = f2bf(v.z); u.w = f2bf(v.w);
        *reinterpret_cast<ushort4*>(out + (long)i * 4) = u;
    }
}

// ---------------------------------------------------------------------------
// Transpose [192][32768] (T) -> [32768][192] (bf16). 64x64 tiles.
template <typename T>
__global__ __launch_bounds__(256) void transpose_cn(
    const T* __restrict__ in, bfr* __restrict__ outT)
{
    __shared__ float sh[64][65];
    const int c0 = blockIdx.y * 64;
    const long n0 = (long)blockIdx.x * 64;
    for (int i = threadIdx.x; i < 64 * 16; i += 256) {
        const int c = i >> 4, n4 = (i & 15) * 4;
        const float4 v = ld4(in + (long)(c0 + c) * N + n0 + n4);
        sh[c][n4 + 0] = v.x; sh[c][n4 + 1] = v.y;
        sh[c][n4 + 2] = v.z; sh[c][n4 + 3] = v.w;
    }
    __syncthreads();
    const int n = threadIdx.x >> 2, seg = threadIdx.x & 3;
    bfr* dst = outT + (n0 + n) * 192 + c0 + seg * 16;
#pragma unroll
    for (int g = 0; g < 4; ++g) {
        ushort4 u;
        u.x = f2bf(sh[seg * 16 + g * 4 + 0][n]);
        u.y = f2bf(sh[seg * 16 + g * 4 + 1][n]);
        u.z = f2bf(sh[seg * 16 + g * 4 + 2][n]);
        u.w = f2bf(sh[seg * 16 + g * 4 + 3][n]);
        *reinterpret_cast<ushort4*>(dst + g * 4) = u;
    }
}

// ---------------------------------------------------------------------------
// MFMA GEMM: Y[o][n] = bias[o] + sum_k A[o][k] * BT[n][k], K=192.
// Block: 256 thr (4 waves 2x2), tile 64(M) x 128(N). K-chunks of 96.
template <typename TY>
__global__ __launch_bounds__(256) void gemm_mfma(
    const bfr* __restrict__ A,    // [O][192] bf16
    const float* __restrict__ bias,
    const bfr* __restrict__ BT,   // [32768][192] bf16
    TY* __restrict__ Y,           // [O][N]
    int OT)                       // O/64
{
    constexpr int KPAD = 104;
    __shared__ short sA[64][KPAD];
    __shared__ short sB[128][KPAD];
    // bijective XCD swizzle (nwg % 8 == 0 here)
    const int nwg = gridDim.x;
    const int wg = blockIdx.x;
    const int xcd = wg & 7, lin = wg >> 3;
    const int q = nwg >> 3, r = nwg & 7;
    const int swz = (xcd < r ? xcd * (q + 1) : r * (q + 1) + (xcd - r) * q) + lin;
    const int o0 = (swz % OT) * 64;
    const long n0 = (long)(swz / OT) * 128;
    const int tid = threadIdx.x;
    const int wave = tid >> 6, lane = tid & 63;
    const int wm = wave & 1, wn = wave >> 1;
    const int lr = lane & 15, lk = lane >> 4;

    f32x4 acc[2][4] = {};
    for (int kc = 0; kc < 192; kc += 96) {
        for (int i = tid; i < 64 * 12; i += 256) {
            const int row = i / 12, c8 = (i % 12) * 8;
            *reinterpret_cast<short8*>(&sA[row][c8]) =
                *reinterpret_cast<const short8*>(&A[(long)(o0 + row) * 192 + kc + c8]);
        }
        for (int i = tid; i < 128 * 12; i += 256) {
            const int row = i / 12, c8 = (i % 12) * 8;
            *reinterpret_cast<short8*>(&sB[row][c8]) =
                *reinterpret_cast<const short8*>(&BT[(n0 + row) * 192 + kc + c8]);
        }
        __syncthreads();
#pragma unroll
        for (int ks = 0; ks < 3; ++ks) {
            short8 af[2], bf[4];
#pragma unroll
            for (int mi = 0; mi < 2; ++mi)
                af[mi] = *reinterpret_cast<const short8*>(&sA[wm * 32 + mi * 16 + lr][ks * 32 + lk * 8]);
#pragma unroll
            for (int ni = 0; ni < 4; ++ni)
                bf[ni] = *reinterpret_cast<const short8*>(&sB[wn * 64 + ni * 16 + lr][ks * 32 + lk * 8]);
#pragma unroll
            for (int mi = 0; mi < 2; ++mi)
#pragma unroll
                for (int ni = 0; ni < 4; ++ni)
                    acc[mi][ni] = mfma16(af[mi], bf[ni], acc[mi][ni]);
        }
        __syncthreads();
    }
    // epilogue: D row=(lane>>4)*4+j, col=lane&15  [m89-verified]
#pragma unroll
    for (int mi = 0; mi < 2; ++mi) {
#pragma unroll
        for (int j = 0; j < 4; ++j) {
            const int o = o0 + wm * 32 + mi * 16 + lk * 4 + j;
            const float bo = bias[o];
#pragma unroll
            for (int ni = 0; ni < 4; ++ni)
                st1(&Y[(long)o * N + n0 + wn * 64 + ni * 16 + lr], acc[mi][ni][j] + bo);
        }
    }
}

// ---------------------------------------------------------------------------
// Depthwise 3x3x3 conv (cross-corr, pad 1) + bias; fused q/k sumsq (fp32).
template <typename T>
__global__ __launch_bounds__(256) void dwconv3(
    const T* __restrict__ in, const float* __restrict__ w,
    const float* __restrict__ bias, T* __restrict__ out,
    float* __restrict__ sq)
{
    __shared__ float sp[3][34][34];
    const int blk = blockIdx.x;
    const int h  = blk & 31;
    const int ch = blk >> 5;
    const T* base = in + (long)ch * N;
    const int tid = threadIdx.x;
    for (int i = tid; i < 34 * 34; i += 256) {
        const int pw = i / 34 - 1, pd = i % 34 - 1;
        const bool inwd = (pw >= 0) && (pw < 32) && (pd >= 0) && (pd < 32);
#pragma unroll
        for (int hp = 0; hp < 3; ++hp) {
            const int hh = h + hp - 1;
            float v = 0.f;
            if (inwd && hh >= 0 && hh < 32) v = ld1(base + hh * 1024 + pw * 32 + pd);
            sp[hp][i / 34][i % 34] = v;
        }
    }
    float wr[27];
#pragma unroll
    for (int j = 0; j < 27; ++j) wr[j] = w[ch * 27 + j];
    const float bs = bias[ch];
    __syncthreads();
    float ssq = 0.f;
    T* outp = out + ((long)ch * 32 + h) * 1024;
    for (int rr = 0; rr < 4; ++rr) {
        const int j = tid + rr * 256;
        const int ww = j >> 5, dd = j & 31;
        float acc2 = bs;
#pragma unroll
        for (int dh = 0; dh < 3; ++dh)
#pragma unroll
            for (int dw2 = 0; dw2 < 3; ++dw2)
#pragma unroll
                for (int dd2 = 0; dd2 < 3; ++dd2)
                    acc2 += wr[(dh * 3 + dw2) * 3 + dd2] * sp[dh][ww + dw2][dd + dd2];
        st1(outp + j, acc2);
        ssq += acc2 * acc2;
    }
    if (ch < 2 * C) {
#pragma unroll
        for (int off = 32; off > 0; off >>= 1) ssq += __shfl_down(ssq, off, 64);
        __shared__ float wsum[4];
        if ((tid & 63) == 0) wsum[tid >> 6] = ssq;
        __syncthreads();
        if (tid == 0) atomicAdd(&sq[ch], wsum[0] + wsum[1] + wsum[2] + wsum[3]);
    }
}

// ---------------------------------------------------------------------------
// Gram via MFMA: attn[h][c][e] += sum_n q[c][n]*k[e][n]. NC=256 per block.
__global__ __launch_bounds__(256) void gram_mfma(
    const bfr* __restrict__ qk,   // dwout: q rows 0..191, k rows 192..383
    float* __restrict__ attn)     // [4][48][48] fp32 (pre-zeroed)
{
    constexpr int NPAD = 264;
    __shared__ short sQ[48][NPAD];
    __shared__ short sK[48][NPAD];
    const int h = blockIdx.x & 3;
    const long nbase = (long)(blockIdx.x >> 2) * 256;
    const bfr* qb = qk + (long)(h * CH) * N + nbase;
    const bfr* kb = qk + (long)(C + h * CH) * N + nbase;
    const int tid = threadIdx.x;
    for (int i = tid; i < 2 * 48 * 32; i += 256) {
        const int t = i >> 11;            // 0: q, 1: k  (48*32 = 1536 ... use explicit)
        const int ii = i & 2047;
        const int row = ii >> 5, c8 = (ii & 31) * 8;
        if (ii < 1536) {
            const bfr* src = (t == 0 ? qb : kb);
            short* dst = (t == 0 ? &sQ[row][c8] : &sK[row][c8]);
            *reinterpret_cast<short8*>(dst) =
                *reinterpret_cast<const short8*>(src + (long)row * N + c8);
        }
    }
    __syncthreads();
    const int wave = tid >> 6, lane = tid & 63;
    const int lr = lane & 15, lk = lane >> 4;
    f32x4 acc[3][3] = {};
#pragma unroll
    for (int w2 = 0; w2 < 2; ++w2) {
        const int ks = wave * 2 + w2;
        short8 aq[3], bk[3];
#pragma unroll
        for (int ct = 0; ct < 3; ++ct)
            aq[ct] = *reinterpret_cast<const short8*>(&sQ[ct * 16 + lr][ks * 32 + lk * 8]);
#pragma unroll
        for (int et = 0; et < 3; ++et)
            bk[et] = *reinterpret_cast<const short8*>(&sK[et * 16 + lr][ks * 32 + lk * 8]);
#pragma unroll
        for (int ct = 0; ct < 3; ++ct)
#pragma unroll
            for (int et = 0; et < 3; ++et)
                acc[ct][et] = mfma16(aq[ct], bk[et], acc[ct][et]);
    }
    float* dst = attn + (long)h * CH * CH;
#pragma unroll
    for (int ct = 0; ct < 3; ++ct)
#pragma unroll
        for (int et = 0; et < 3; ++et)
#pragma unroll
            for (int j = 0; j < 4; ++j)
                atomicAdd(&dst[(ct * 16 + lk * 4 + j) * CH + et * 16 + lr], acc[ct][et][j]);
}

// ---------------------------------------------------------------------------
__global__ __launch_bounds__(64) void softmax_scale(
    float* __restrict__ attn, const float* __restrict__ sq,
    const float* __restrict__ temp)
{
    const int h = blockIdx.x;
    const int c = threadIdx.x;
    if (c >= CH) return;
    const float invq = 1.0f / fmaxf(sqrtf(sq[h * CH + c]), EPSN);
    const float t = temp[h];
    float* row = attn + ((long)h * CH + c) * CH;
    float vals[CH];
    float mx = -3.4e38f;
#pragma unroll
    for (int e = 0; e < CH; ++e) {
        const float invk = 1.0f / fmaxf(sqrtf(sq[C + h * CH + e]), EPSN);
        const float v = row[e] * invq * invk * t;
        vals[e] = v;
        mx = fmaxf(mx, v);
    }
    float sum = 0.f;
#pragma unroll
    for (int e = 0; e < CH; ++e) { vals[e] = expf(vals[e] - mx); sum += vals[e]; }
    const float inv = 1.0f / sum;
#pragma unroll
    for (int e = 0; e < CH; ++e) row[e] = vals[e] * inv;
}

// ---------------------------------------------------------------------------
// M[o][h*48+e] = sum_c P[o][h*48+c]*attn[h][c][e]  (bf16 out for MFMA B-use)
__global__ __launch_bounds__(192) void build_m(
    const float* __restrict__ P, const float* __restrict__ attn,
    bfr* __restrict__ M)
{
    const int o = blockIdx.x;
    const int he = threadIdx.x;
    const int h = he / CH, e = he % CH;
    float s = 0.f;
#pragma unroll
    for (int cc = 0; cc < CH; ++cc)
        s += P[o * C + h * CH + cc] * attn[((long)h * CH + cc) * CH + e];
    M[(long)o * C + he] = f2bf(s);
}

// ---------------------------------------------------------------------------
extern "C" void kernel_launch(void* const* d_in, const int* in_sizes, int n_in,
                              void* d_out, int out_size, void* d_ws, size_t ws_size,
                              hipStream_t stream)
{
    const float* x      = (const float*)d_in[0];
    const float* qkv_w  = (const float*)d_in[1];
    const float* qkv_b  = (const float*)d_in[2];
    const float* dw_w   = (const float*)d_in[3];
    const float* dw_b   = (const float*)d_in[4];
    const float* proj_w = (const float*)d_in[5];
    const float* proj_b = (const float*)d_in[6];
    const float* temp   = (const float*)d_in[7];
    float* out = (float*)d_out;

    float* sq   = (float*)d_ws;            // [2][384]
    float* attn = sq + 2 * 384;            // [2][4*48*48]
    bfr*  w_bf  = (bfr*)(attn + 2 * HEADS * CH * CH);  // [576*192]
    bfr*  M_bf  = w_bf + C3 * C;           // [2][192*192]
    bfr*  xT    = M_bf + 2 * C * C;        // [32768*192]
    bfr*  vT    = xT + N * C;              // [32768*192]
    bfr*  qkv   = vT + N * C;              // [576*32768]
    bfr*  dwout = qkv + C3 * N;            // [576*32768]

    hipMemsetAsync(d_ws, 0, (2 * 384 + 2 * HEADS * CH * CH) * sizeof(float), stream);

    // weights -> bf16 (once)
    convert_bf<<<(C3 * C / 4 + 255) / 256, 256, 0, stream>>>(qkv_w, w_bf, C3 * C / 4);

    for (int b = 0; b < 2; ++b) {
        const float* x_b   = x + (long)b * C * N;
        float*       out_b = out + (long)b * C * N;
        float* sq_b   = sq + b * 384;
        float* attn_b = attn + b * HEADS * CH * CH;
        bfr*   M_b    = M_bf + b * C * C;

        // x -> xT bf16 [n][192]
        transpose_cn<float><<<dim3((unsigned)(N / 64), C / 64), 256, 0, stream>>>(x_b, xT);
        // qkv = W @ x  (MFMA)
        gemm_mfma<bfr><<<(unsigned)((N / 128) * (C3 / 64)), 256, 0, stream>>>(
            w_bf, qkv_b, xT, qkv, C3 / 64);
        // depthwise conv + sumsq
        dwconv3<bfr><<<C3 * S, 256, 0, stream>>>(qkv, dw_w, dw_b, dwout, sq_b);
        // v -> vT bf16
        transpose_cn<bfr><<<dim3((unsigned)(N / 64), C / 64), 256, 0, stream>>>(
            dwout + 2L * C * N, vT);
        // gram
        gram_mfma<<<(unsigned)(HEADS * (N / 256)), 256, 0, stream>>>(dwout, attn_b);
        // softmax
        softmax_scale<<<HEADS, 64, 0, stream>>>(attn_b, sq_b, temp);
        // M = P @ attn (bf16)
        build_m<<<C, 192, 0, stream>>>(proj_w, attn_b, M_b);
        // out = M @ v + proj_b  (MFMA, fp32 out)
        gemm_mfma<float><<<(unsigned)((N / 128) * (C / 64)), 256, 0, stream>>>(
            M_b, proj_b, vT, out_b, C / 64);
    }
}

// Round 4
// 297.304 us; speedup vs baseline: 2.2821x; 1.5459x over previous
//
#include <hip/hip_runtime.h>

// Attention_41601053229865 — fused 3D channel attention, bf16-MFMA, batched.
// B=2, C=192 (4 heads x 48), spatial 32^3 = 32768.

typedef unsigned short bfr;   // raw bf16 storage

constexpr int C = 192, C3 = 576, S = 32, HEADS = 4, CH = 48;
constexpr long N = 32768;            // 32^3
constexpr long CHN = (long)C3 * N;   // 18,874,368
#define EPSN 1e-12f

using short8 = __attribute__((ext_vector_type(8))) short;
using f32x4  = __attribute__((ext_vector_type(4))) float;

__device__ __forceinline__ float bf2f(bfr h) { return __uint_as_float(((unsigned)h) << 16); }
__device__ __forceinline__ bfr f2bf(float f) {
    unsigned u = __float_as_uint(f);
    return (bfr)((u + 0x7fffu + ((u >> 16) & 1u)) >> 16);
}
__device__ __forceinline__ float ld1(const float* p) { return *p; }
__device__ __forceinline__ float ld1(const bfr* p) { return bf2f(*p); }
__device__ __forceinline__ void st1(float* p, float v) { *p = v; }
__device__ __forceinline__ void st1(bfr* p, float v) { *p = f2bf(v); }
__device__ __forceinline__ float4 ld4(const float* p) { return *reinterpret_cast<const float4*>(p); }
__device__ __forceinline__ float4 ld4(const bfr* p) {
    ushort4 u = *reinterpret_cast<const ushort4*>(p);
    float4 r; r.x = bf2f(u.x); r.y = bf2f(u.y); r.z = bf2f(u.z); r.w = bf2f(u.w); return r;
}
__device__ __forceinline__ void ld8f(const bfr* p, float* o) {
    short8 u = *reinterpret_cast<const short8*>(p);
#pragma unroll
    for (int e = 0; e < 8; ++e) o[e] = bf2f((bfr)u[e]);
}

__device__ __forceinline__ f32x4 mfma16(short8 a, short8 b, f32x4 c) {
    return __builtin_amdgcn_mfma_f32_16x16x32_bf16(a, b, c, 0, 0, 0);
}

// ---------------------------------------------------------------------------
__global__ __launch_bounds__(256) void convert_bf(
    const float* __restrict__ in, bfr* __restrict__ out, int n4)
{
    const int i = blockIdx.x * 256 + threadIdx.x;
    if (i < n4) {
        const float4 v = *reinterpret_cast<const float4*>(in + (long)i * 4);
        ushort4 u;
        u.x = f2bf(v.x); u.y = f2bf(v.y); u.z = f2bf(v.z); u.w = f2bf(v.w);
        *reinterpret_cast<ushort4*>(out + (long)i * 4) = u;
    }
}

// ---------------------------------------------------------------------------
// Transpose [192][N] -> [N][192] bf16. 64x64 tiles; blockIdx.z = batch.
template <typename T>
__global__ __launch_bounds__(256) void transpose_cn(
    const T* __restrict__ in, long in_bstride,
    bfr* __restrict__ outT, long out_bstride)
{
    __shared__ float sh[64][65];
    const T* inb = in + blockIdx.z * in_bstride;
    bfr* outb = outT + blockIdx.z * out_bstride;
    const int c0 = blockIdx.y * 64;
    const long n0 = (long)blockIdx.x * 64;
    for (int i = threadIdx.x; i < 64 * 16; i += 256) {
        const int c = i >> 4, n4 = (i & 15) * 4;
        const float4 v = ld4(inb + (long)(c0 + c) * N + n0 + n4);
        sh[c][n4 + 0] = v.x; sh[c][n4 + 1] = v.y;
        sh[c][n4 + 2] = v.z; sh[c][n4 + 3] = v.w;
    }
    __syncthreads();
    const int n = threadIdx.x >> 2, seg = threadIdx.x & 3;
    bfr* dst = outb + (n0 + n) * 192 + c0 + seg * 16;
#pragma unroll
    for (int g = 0; g < 4; ++g) {
        ushort4 u;
        u.x = f2bf(sh[seg * 16 + g * 4 + 0][n]);
        u.y = f2bf(sh[seg * 16 + g * 4 + 1][n]);
        u.z = f2bf(sh[seg * 16 + g * 4 + 2][n]);
        u.w = f2bf(sh[seg * 16 + g * 4 + 3][n]);
        *reinterpret_cast<ushort4*>(dst + g * 4) = u;
    }
}

// ---------------------------------------------------------------------------
// MFMA GEMM: Y[o][n] = bias[o] + sum_k A[o][k]*BT[n][k], K=192. z = batch.
template <typename TY>
__global__ __launch_bounds__(256) void gemm_mfma(
    const bfr* __restrict__ A, long a_bstride,
    const float* __restrict__ bias,
    const bfr* __restrict__ BT, long bt_bstride,
    TY* __restrict__ Y, long y_bstride,
    int OT)
{
    constexpr int KPAD = 104;
    __shared__ short sA[64][KPAD];
    __shared__ short sB[128][KPAD];
    const bfr* Ab = A + blockIdx.z * a_bstride;
    const bfr* BTb = BT + blockIdx.z * bt_bstride;
    TY* Yb = Y + blockIdx.z * y_bstride;
    const int nwg = gridDim.x;
    const int wg = blockIdx.x;
    const int xcd = wg & 7, lin = wg >> 3;
    const int q = nwg >> 3, r = nwg & 7;
    const int swz = (xcd < r ? xcd * (q + 1) : r * (q + 1) + (xcd - r) * q) + lin;
    const int o0 = (swz % OT) * 64;
    const long n0 = (long)(swz / OT) * 128;
    const int tid = threadIdx.x;
    const int wave = tid >> 6, lane = tid & 63;
    const int wm = wave & 1, wn = wave >> 1;
    const int lr = lane & 15, lk = lane >> 4;

    f32x4 acc[2][4] = {};
    for (int kc = 0; kc < 192; kc += 96) {
        for (int i = tid; i < 64 * 12; i += 256) {
            const int row = i / 12, c8 = (i % 12) * 8;
            *reinterpret_cast<short8*>(&sA[row][c8]) =
                *reinterpret_cast<const short8*>(&Ab[(long)(o0 + row) * 192 + kc + c8]);
        }
        for (int i = tid; i < 128 * 12; i += 256) {
            const int row = i / 12, c8 = (i % 12) * 8;
            *reinterpret_cast<short8*>(&sB[row][c8]) =
                *reinterpret_cast<const short8*>(&BTb[(n0 + row) * 192 + kc + c8]);
        }
        __syncthreads();
#pragma unroll
        for (int ks = 0; ks < 3; ++ks) {
            short8 af[2], bf[4];
#pragma unroll
            for (int mi = 0; mi < 2; ++mi)
                af[mi] = *reinterpret_cast<const short8*>(&sA[wm * 32 + mi * 16 + lr][ks * 32 + lk * 8]);
#pragma unroll
            for (int ni = 0; ni < 4; ++ni)
                bf[ni] = *reinterpret_cast<const short8*>(&sB[wn * 64 + ni * 16 + lr][ks * 32 + lk * 8]);
#pragma unroll
            for (int mi = 0; mi < 2; ++mi)
#pragma unroll
                for (int ni = 0; ni < 4; ++ni)
                    acc[mi][ni] = mfma16(af[mi], bf[ni], acc[mi][ni]);
        }
        __syncthreads();
    }
#pragma unroll
    for (int mi = 0; mi < 2; ++mi) {
#pragma unroll
        for (int j = 0; j < 4; ++j) {
            const int o = o0 + wm * 32 + mi * 16 + lk * 4 + j;
            const float bo = bias[o];
#pragma unroll
            for (int ni = 0; ni < 4; ++ni)
                st1(&Yb[(long)o * N + n0 + wn * 64 + ni * 16 + lr], acc[mi][ni][j] + bo);
        }
    }
}

// ---------------------------------------------------------------------------
// Depthwise 3x3x3 conv + bias, fused q/k sumsq. Block = (ch, 8 h-planes);
// grid (2304, 2). Stages 10 fp32 planes [10][34][38] in LDS, one barrier.
__global__ __launch_bounds__(256) void dwconv3(
    const bfr* __restrict__ in, const float* __restrict__ w,
    const float* __restrict__ bias, bfr* __restrict__ out,
    float* __restrict__ sq)
{
    __shared__ float sp[10][34][38];
    const int blk = blockIdx.x;
    const int bb = blockIdx.y;
    const int hg = blk & 3;
    const int ch = blk >> 2;
    const int h0 = hg * 8;
    const bfr* base = in + bb * CHN + (long)ch * N;
    const int tid = threadIdx.x;

    // interior rows: 10 planes x 32 w-rows, vector loads
    for (int r2 = tid; r2 < 320; r2 += 256) {
        const int p = r2 >> 5, ww = r2 & 31;
        const int hh = h0 - 1 + p;
        if (hh >= 0 && hh < 32) {
            const bfr* rp = base + hh * 1024 + ww * 32;
            float vals[32];
            ld8f(rp, vals); ld8f(rp + 8, vals + 8);
            ld8f(rp + 16, vals + 16); ld8f(rp + 24, vals + 24);
#pragma unroll
            for (int e = 0; e < 32; ++e) sp[p][ww + 1][e + 1] = vals[e];
        } else {
#pragma unroll
            for (int e = 0; e < 32; ++e) sp[p][ww + 1][e + 1] = 0.f;
        }
    }
    // halos
    for (int r2 = tid; r2 < 340; r2 += 256) {
        const int p = r2 / 34, a = r2 % 34;
        sp[p][a][0] = 0.f; sp[p][a][33] = 0.f;
        sp[p][0][a] = 0.f; sp[p][33][a] = 0.f;
    }
    float wr[27];
#pragma unroll
    for (int j = 0; j < 27; ++j) wr[j] = w[ch * 27 + j];
    const float bs = bias[ch];
    __syncthreads();

    float ssq = 0.f;
    bfr* outb = out + bb * CHN + (long)ch * N;
#pragma unroll
    for (int t = 0; t < 2; ++t) {
        const int s = tid + t * 256;
        const int p = s >> 6, w0 = ((s >> 3) & 7) * 4, d0 = (s & 7) * 4;
        float acc[4][4];
#pragma unroll
        for (int i = 0; i < 4; ++i)
#pragma unroll
            for (int j = 0; j < 4; ++j) acc[i][j] = bs;
#pragma unroll
        for (int dh = 0; dh < 3; ++dh)
#pragma unroll
            for (int dw2 = 0; dw2 < 3; ++dw2)
#pragma unroll
                for (int dd2 = 0; dd2 < 3; ++dd2) {
                    const float wv = wr[(dh * 3 + dw2) * 3 + dd2];
#pragma unroll
                    for (int i = 0; i < 4; ++i)
#pragma unroll
                        for (int j = 0; j < 4; ++j)
                            acc[i][j] += wv * sp[p + dh][w0 + i + dw2][d0 + j + dd2];
                }
        bfr* op = outb + ((h0 + p) * 32 + w0) * 32 + d0;
#pragma unroll
        for (int i = 0; i < 4; ++i) {
            ushort4 u;
            u.x = f2bf(acc[i][0]); u.y = f2bf(acc[i][1]);
            u.z = f2bf(acc[i][2]); u.w = f2bf(acc[i][3]);
            *reinterpret_cast<ushort4*>(op + i * 32) = u;
#pragma unroll
            for (int j = 0; j < 4; ++j) ssq += acc[i][j] * acc[i][j];
        }
    }
    if (ch < 2 * C) {
#pragma unroll
        for (int off = 32; off > 0; off >>= 1) ssq += __shfl_down(ssq, off, 64);
        __shared__ float wsum[4];
        if ((tid & 63) == 0) wsum[tid >> 6] = ssq;
        __syncthreads();
        if (tid == 0) atomicAdd(&sq[bb * 384 + ch], wsum[0] + wsum[1] + wsum[2] + wsum[3]);
    }
}

// ---------------------------------------------------------------------------
// Gram via MFMA: attn[h][c][e] += sum_n q[c][n]*k[e][n]. grid (512, 2).
__global__ __launch_bounds__(256) void gram_mfma(
    const bfr* __restrict__ qk, float* __restrict__ attn)
{
    constexpr int NPAD = 264;
    __shared__ short sQ[48][NPAD];
    __shared__ short sK[48][NPAD];
    const int bb = blockIdx.y;
    const int h = blockIdx.x & 3;
    const long nbase = (long)(blockIdx.x >> 2) * 256;
    const bfr* qb = qk + bb * CHN + (long)(h * CH) * N + nbase;
    const bfr* kb = qk + bb * CHN + (long)(C + h * CH) * N + nbase;
    const int tid = threadIdx.x;
    for (int i = tid; i < 1536; i += 256) {
        const int row = i >> 5, c8 = (i & 31) * 8;
        *reinterpret_cast<short8*>(&sQ[row][c8]) =
            *reinterpret_cast<const short8*>(qb + (long)row * N + c8);
        *reinterpret_cast<short8*>(&sK[row][c8]) =
            *reinterpret_cast<const short8*>(kb + (long)row * N + c8);
    }
    __syncthreads();
    const int wave = tid >> 6, lane = tid & 63;
    const int lr = lane & 15, lk = lane >> 4;
    f32x4 acc[3][3] = {};
#pragma unroll
    for (int w2 = 0; w2 < 2; ++w2) {
        const int ks = wave * 2 + w2;
        short8 aq[3], bk[3];
#pragma unroll
        for (int ct = 0; ct < 3; ++ct)
            aq[ct] = *reinterpret_cast<const short8*>(&sQ[ct * 16 + lr][ks * 32 + lk * 8]);
#pragma unroll
        for (int et = 0; et < 3; ++et)
            bk[et] = *reinterpret_cast<const short8*>(&sK[et * 16 + lr][ks * 32 + lk * 8]);
#pragma unroll
        for (int ct = 0; ct < 3; ++ct)
#pragma unroll
            for (int et = 0; et < 3; ++et)
                acc[ct][et] = mfma16(aq[ct], bk[et], acc[ct][et]);
    }
    float* dst = attn + bb * HEADS * CH * CH + (long)h * CH * CH;
#pragma unroll
    for (int ct = 0; ct < 3; ++ct)
#pragma unroll
        for (int et = 0; et < 3; ++et)
#pragma unroll
            for (int j = 0; j < 4; ++j)
                atomicAdd(&dst[(ct * 16 + lk * 4 + j) * CH + et * 16 + lr], acc[ct][et][j]);
}

// ---------------------------------------------------------------------------
__global__ __launch_bounds__(64) void softmax_scale(
    float* __restrict__ attn, const float* __restrict__ sq,
    const float* __restrict__ temp)
{
    const int bb = blockIdx.x >> 2, h = blockIdx.x & 3;
    const int c = threadIdx.x;
    if (c >= CH) return;
    const float* sqb = sq + bb * 384;
    const float invq = 1.0f / fmaxf(sqrtf(sqb[h * CH + c]), EPSN);
    const float t = temp[h];
    float* row = attn + bb * HEADS * CH * CH + ((long)h * CH + c) * CH;
    float vals[CH];
    float mx = -3.4e38f;
#pragma unroll
    for (int e = 0; e < CH; ++e) {
        const float invk = 1.0f / fmaxf(sqrtf(sqb[C + h * CH + e]), EPSN);
        const float v = row[e] * invq * invk * t;
        vals[e] = v;
        mx = fmaxf(mx, v);
    }
    float sum = 0.f;
#pragma unroll
    for (int e = 0; e < CH; ++e) { vals[e] = expf(vals[e] - mx); sum += vals[e]; }
    const float inv = 1.0f / sum;
#pragma unroll
    for (int e = 0; e < CH; ++e) row[e] = vals[e] * inv;
}

// ---------------------------------------------------------------------------
__global__ __launch_bounds__(192) void build_m(
    const float* __restrict__ P, const float* __restrict__ attn,
    bfr* __restrict__ M)
{
    const int bb = blockIdx.y;
    const int o = blockIdx.x;
    const int he = threadIdx.x;
    const int h = he / CH, e = he % CH;
    const float* attb = attn + bb * HEADS * CH * CH;
    float s = 0.f;
#pragma unroll
    for (int cc = 0; cc < CH; ++cc)
        s += P[o * C + h * CH + cc] * attb[((long)h * CH + cc) * CH + e];
    M[(long)bb * C * C + (long)o * C + he] = f2bf(s);
}

// ---------------------------------------------------------------------------
extern "C" void kernel_launch(void* const* d_in, const int* in_sizes, int n_in,
                              void* d_out, int out_size, void* d_ws, size_t ws_size,
                              hipStream_t stream)
{
    const float* x      = (const float*)d_in[0];
    const float* qkv_w  = (const float*)d_in[1];
    const float* qkv_b  = (const float*)d_in[2];
    const float* dw_w   = (const float*)d_in[3];
    const float* dw_b   = (const float*)d_in[4];
    const float* proj_w = (const float*)d_in[5];
    const float* proj_b = (const float*)d_in[6];
    const float* temp   = (const float*)d_in[7];
    float* out = (float*)d_out;

    float* sq   = (float*)d_ws;                        // [2][384]
    float* attn = sq + 2 * 384;                        // [2][9216]
    bfr*  w_bf  = (bfr*)(attn + 2 * HEADS * CH * CH);  // [576*192]
    bfr*  M_bf  = w_bf + C3 * C;                       // [2][192*192]
    bfr*  xT    = M_bf + 2 * C * C;                    // [2][N*192]
    bfr*  vT    = xT + 2 * N * C;                      // [2][N*192]
    bfr*  qkv   = vT + 2 * N * C;                      // [2][576*N]
    bfr*  dwout = qkv + 2 * CHN;                       // [2][576*N]

    hipMemsetAsync(d_ws, 0, (2 * 384 + 2 * HEADS * CH * CH) * sizeof(float), stream);

    convert_bf<<<(C3 * C / 4 + 255) / 256, 256, 0, stream>>>(qkv_w, w_bf, C3 * C / 4);

    // x -> xT bf16 [n][192] (both batches)
    transpose_cn<float><<<dim3((unsigned)(N / 64), C / 64, 2), 256, 0, stream>>>(
        x, (long)C * N, xT, N * 192L);
    // qkv = W @ x
    gemm_mfma<bfr><<<dim3((unsigned)((N / 128) * (C3 / 64)), 1, 2), 256, 0, stream>>>(
        w_bf, 0L, qkv_b, xT, N * 192L, qkv, CHN, C3 / 64);
    // depthwise conv + sumsq
    dwconv3<<<dim3(C3 * 4, 2), 256, 0, stream>>>(qkv, dw_w, dw_b, dwout, sq);
    // v -> vT
    transpose_cn<bfr><<<dim3((unsigned)(N / 64), C / 64, 2), 256, 0, stream>>>(
        dwout + 2L * C * N, CHN, vT, N * 192L);
    // gram
    gram_mfma<<<dim3((unsigned)(HEADS * (N / 256) / 4), 2), 256, 0, stream>>>(dwout, attn);
    // softmax
    softmax_scale<<<2 * HEADS, 64, 0, stream>>>(attn, sq, temp);
    // M = P @ attn
    build_m<<<dim3(C, 2), 192, 0, stream>>>(proj_w, attn, M_bf);
    // out = M @ v + proj_b
    gemm_mfma<float><<<dim3((unsigned)((N / 128) * (C / 64)), 1, 2), 256, 0, stream>>>(
        M_bf, (long)C * C, proj_b, vT, N * 192L, out, (long)C * N, C / 64);
}